// Round 5
// baseline (283.786 us; speedup 1.0000x reference)
//
#include <hip/hip_runtime.h>

typedef _Float16 f16;
typedef _Float16 f16x8 __attribute__((ext_vector_type(8)));
typedef float f32x4 __attribute__((ext_vector_type(4)));

#define XNS 264   // xn row stride (528B, 16B-mult)
#define QKS 40    // q/k row stride (80B)
#define VTS 72    // vt row stride (144B)
#define PSS 72    // p row stride (144B)
#define ALS 72    // attn-out tile row stride (144B)

__device__ __forceinline__ f32x4 mfma16(f16x8 a, f16x8 b, f32x4 c){
  return __builtin_amdgcn_mfma_f32_16x16x32_f16(a, b, c, 0, 0, 0);
}

// ---------------- kernel 0: weights fp32 -> fp16 ----------------
__global__ __launch_bounds__(256) void k_cvt(const float* __restrict__ wqkv,
                                             const float* __restrict__ wproj,
                                             f16* __restrict__ wqkv_h,
                                             f16* __restrict__ wproj_h){
  int i = blockIdx.x*256 + threadIdx.x;
  for (int idx = i; idx < 768*256; idx += gridDim.x*256) wqkv_h[idx] = (f16)wqkv[idx];
  for (int idx = i; idx < 256*256; idx += gridDim.x*256) wproj_h[idx] = (f16)wproj[idx];
}

// ---------------- fused: LN + QKV + attention + proj, 72.7KB LDS -> 2 blocks/CU ----------------
// Block = row (b,hh), 512 thr = 8 waves = 2 head-slots x 4 waves. 4 iterations x 2 heads.
// Per iter: slot s computes head 2*iter+s (QKV -> S -> softmax -> PV -> alit), then ALL
// waves accumulate a K=64 slice of the out-proj into persistent registers.
__global__ __launch_bounds__(512, 4) void k_fused(const float* __restrict__ x,
    const float* __restrict__ gamma, const float* __restrict__ beta,
    const f16* __restrict__ wqkv, const f16* __restrict__ wproj,
    const float* __restrict__ bproj, float* __restrict__ out)
{
  __shared__ __align__(16) f16 xn[64*XNS];      // 33792 B (never overwritten)
  __shared__ __align__(16) f16 slot[2][7424];   // 29696 B: qs[0:2560) ks[2560:5120) vt[5120:7424); ps overlays [0:4608)
  __shared__ __align__(16) f16 alit[64*ALS];    // 9216 B: per-iter attn-out (64 pos x 64 ch)
  float* red = (float*)&slot[0][0];             // [2][8][64] f32 overlay (dead before first QKV)
  float* mrs = (float*)&slot[0][2048];          // [2][64] f32 overlay

  const int t = threadIdx.x;
  const int lane = t & 63;
  const int h = t >> 6;                 // wave id
  const int s = h >> 2, ws = h & 3;     // head-slot, wave-in-slot
  const int l15 = lane & 15, l16 = lane >> 4;
  const int row = blockIdx.x;
  const int b = row >> 6, hh = row & 63;
  const float* xrow = x + (size_t)b*256*4096 + hh*64;

  // ---- phase A: float4 x loads -> raw f16 into xn (transposed) ----
  {
    int c = t >> 1, wh = t & 1;
    const float4* src = (const float4*)(xrow + (size_t)c*4096 + wh*32);
    for (int j = 0; j < 8; ++j){
      float4 v = src[j];
      int w = wh*32 + j*4;
      xn[(w+0)*XNS + c] = (f16)v.x;
      xn[(w+1)*XNS + c] = (f16)v.y;
      xn[(w+2)*XNS + c] = (f16)v.z;
      xn[(w+3)*XNS + c] = (f16)v.w;
    }
  }
  __syncthreads();

  // ---- stats from LDS: (wave h, lane) -> w=lane, channels h*32..+31 ----
  {
    float ssum = 0.f, s2 = 0.f;
    for (int j8 = 0; j8 < 4; ++j8){
      f16x8 v = *(const f16x8*)&xn[lane*XNS + h*32 + j8*8];
      for (int e = 0; e < 8; ++e){ float f = (float)v[e]; ssum += f; s2 += f*f; }
    }
    red[(0*8 + h)*64 + lane] = ssum;
    red[(1*8 + h)*64 + lane] = s2;
  }
  __syncthreads();
  if (t < 64){
    float ss = 0.f, qq = 0.f;
    for (int j = 0; j < 8; ++j){ ss += red[j*64 + t]; qq += red[(8+j)*64 + t]; }
    float mu = ss*(1.f/256.f);
    float var = qq*(1.f/256.f) - mu*mu;
    mrs[t] = mu; mrs[64 + t] = rsqrtf(var + 1e-5f);
  }
  __syncthreads();
  // ---- normalize in place ----
  {
    float mu = mrs[lane], rs = mrs[64 + lane];
    for (int j8 = 0; j8 < 4; ++j8){
      f16x8 v = *(const f16x8*)&xn[lane*XNS + h*32 + j8*8];
      f16x8 o;
      for (int e = 0; e < 8; ++e){
        int c = h*32 + j8*8 + e;
        o[e] = (f16)(((float)v[e] - mu)*rs*gamma[c] + beta[c]);
      }
      *(f16x8*)&xn[lane*XNS + h*32 + j8*8] = o;
    }
  }
  __syncthreads();

  f16* qs  = &slot[s][0];
  f16* ks  = &slot[s][2560];
  f16* vts = &slot[s][5120];
  f16* ps  = &slot[s][0];      // overlays qs+ks after barrier B2

  f32x4 pacc[4][2] = {};       // persistent out-proj accumulators (32 VGPR)

  for (int iter = 0; iter < 4; ++iter){
    const int head = iter*2 + s;
    // ---- QKV GEMMs for this slot's head ----
    for (int qk = 0; qk < 2; ++qk){
      const f16* wb = wqkv + (size_t)(qk*256 + head*32)*256;
      f32x4 acc[2] = {};
      for (int kk = 0; kk < 8; ++kk){
        int k0 = kk*32 + l16*8;
        f16x8 a  = *(const f16x8*)&xn[(ws*16 + l15)*XNS + k0];
        f16x8 b0 = *(const f16x8*)&wb[(size_t)(l15)*256 + k0];
        f16x8 b1 = *(const f16x8*)&wb[(size_t)(16 + l15)*256 + k0];
        acc[0] = mfma16(a, b0, acc[0]);
        acc[1] = mfma16(a, b1, acc[1]);
      }
      f16* dst = qk ? ks : qs;
      for (int n = 0; n < 2; ++n)
        for (int r = 0; r < 4; ++r){
          int pos = ws*16 + l16*4 + r;
          dst[pos*QKS + n*16 + l15] = (f16)acc[n][r];
        }
    }
    {   // V swapped -> vt[d][pos]; wave ws -> m=ws>>1, n-pair=(ws&1)*2
      const f16* wv = wqkv + (size_t)(512 + head*32)*256;
      int mV = ws >> 1, nB = (ws & 1)*2;
      f32x4 acc[2] = {};
      for (int kk = 0; kk < 8; ++kk){
        int k0 = kk*32 + l16*8;
        f16x8 a  = *(const f16x8*)&wv[(size_t)(mV*16 + l15)*256 + k0];
        f16x8 b0 = *(const f16x8*)&xn[((nB+0)*16 + l15)*XNS + k0];
        f16x8 b1 = *(const f16x8*)&xn[((nB+1)*16 + l15)*XNS + k0];
        acc[0] = mfma16(a, b0, acc[0]);
        acc[1] = mfma16(a, b1, acc[1]);
      }
      for (int n = 0; n < 2; ++n)
        for (int r = 0; r < 4; ++r){
          int d   = mV*16 + l16*4 + r;
          int pos = (nB+n)*16 + l15;
          vts[d*VTS + pos] = (f16)acc[n][r];
        }
    }
    __syncthreads();   // B1: qs/ks/vt visible

    // ---- S = Q K^T: wave ws owns q-rows ws*16..+15, all 4 kpos tiles (K=32 = one MFMA) ----
    f32x4 sa[4];
    {
      f16x8 a = *(const f16x8*)&qs[(ws*16 + l15)*QKS + l16*8];
      f32x4 z = {0.f,0.f,0.f,0.f};
      for (int n = 0; n < 4; ++n){
        f16x8 bb = *(const f16x8*)&ks[(n*16 + l15)*QKS + l16*8];
        sa[n] = mfma16(a, bb, z);
      }
    }
    __syncthreads();   // B2: all S reads done; ps may overlay qs/ks

    // ---- softmax (reduce across l15-group) + P write (own rows) ----
    {
      const float sc = 0.17677669529663687f;   // 32^-0.5
      for (int r = 0; r < 4; ++r){
        float mx = fmaxf(fmaxf(sa[0][r], sa[1][r]), fmaxf(sa[2][r], sa[3][r]));
        mx = fmaxf(mx, __shfl_xor(mx, 1));
        mx = fmaxf(mx, __shfl_xor(mx, 2));
        mx = fmaxf(mx, __shfl_xor(mx, 4));
        mx = fmaxf(mx, __shfl_xor(mx, 8));
        float pv[4], sum = 0.f;
        for (int n = 0; n < 4; ++n){ float p = __expf((sa[n][r] - mx)*sc); pv[n] = p; sum += p; }
        sum += __shfl_xor(sum, 1);
        sum += __shfl_xor(sum, 2);
        sum += __shfl_xor(sum, 4);
        sum += __shfl_xor(sum, 8);
        float inv = 1.f/sum;
        int q = ws*16 + l16*4 + r;
        for (int n = 0; n < 4; ++n) ps[q*PSS + n*16 + l15] = (f16)(pv[n]*inv);
      }
    }
    // ---- PV (A rows wave-local -> no barrier; vt covered by B1) ----
    {
      f32x4 oa[2] = {};
      for (int kk = 0; kk < 2; ++kk){
        int k0 = kk*32 + l16*8;
        f16x8 a = *(const f16x8*)&ps[(ws*16 + l15)*PSS + k0];
        for (int n = 0; n < 2; ++n){
          f16x8 bb = *(const f16x8*)&vts[(n*16 + l15)*VTS + k0];
          oa[n] = mfma16(a, bb, oa[n]);
        }
      }
      for (int n = 0; n < 2; ++n)
        for (int r = 0; r < 4; ++r){
          int pos = ws*16 + l16*4 + r;
          alit[pos*ALS + s*32 + n*16 + l15] = (f16)oa[n][r];
        }
    }
    __syncthreads();   // B3: alit complete (also: slot safe to overwrite next iter)

    // ---- partial out-proj: K-slice iter*64..+64; wave h -> dout h*32..+31 ----
    for (int kk = 0; kk < 2; ++kk){
      int k0 = kk*32 + l16*8;
      f16x8 a[4], bb[2];
      for (int m = 0; m < 4; ++m) a[m] = *(const f16x8*)&alit[(m*16 + l15)*ALS + k0];
      for (int n = 0; n < 2; ++n)
        bb[n] = *(const f16x8*)&wproj[(size_t)(h*32 + n*16 + l15)*256 + iter*64 + k0];
      for (int m = 0; m < 4; ++m)
        for (int n = 0; n < 2; ++n)
          pacc[m][n] = mfma16(a[m], bb[n], pacc[m][n]);
    }
  }

  // ---- epilogue: bias + direct f32x4 stores (4 consecutive w per lane) ----
  {
    float bia[2];
    for (int n = 0; n < 2; ++n) bia[n] = bproj[h*32 + n*16 + l15];
    float* obase = out + (size_t)b*256*4096 + hh*64;
    for (int m = 0; m < 4; ++m)
      for (int n = 0; n < 2; ++n){
        int dout = h*32 + n*16 + l15;
        f32x4 v;
        for (int r = 0; r < 4; ++r) v[r] = pacc[m][n][r] + bia[n];
        *(f32x4*)&obase[(size_t)dout*4096 + m*16 + l16*4] = v;
      }
  }
}

extern "C" void kernel_launch(void* const* d_in, const int* in_sizes, int n_in,
                              void* d_out, int out_size, void* d_ws, size_t ws_size,
                              hipStream_t stream)
{
  const float* x     = (const float*)d_in[0];
  const float* wqkv  = (const float*)d_in[1];
  const float* wproj = (const float*)d_in[2];
  const float* bproj = (const float*)d_in[3];
  const float* gamma = (const float*)d_in[4];
  const float* beta  = (const float*)d_in[5];
  float* out = (float*)d_out;

  f16* ws = (f16*)d_ws;
  f16* wqkv_h  = ws;            // 196608 f16
  f16* wproj_h = ws + 196608;   // 65536 f16

  k_cvt  <<<256, 256, 0, stream>>>(wqkv, wproj, wqkv_h, wproj_h);
  k_fused<<<1024, 512, 0, stream>>>(x, gamma, beta, wqkv_h, wproj_h, bproj, out);
}

// Round 7
// 211.445 us; speedup vs baseline: 1.3421x; 1.3421x over previous
//
#include <hip/hip_runtime.h>

typedef _Float16 f16;
typedef _Float16 f16x8 __attribute__((ext_vector_type(8)));
typedef float f32x4 __attribute__((ext_vector_type(4)));

#define XNS 264   // xn/al row stride in f16 (528B = 33*16B)
#define QKS 40    // q/k row stride (80B)
#define VTS 72    // vt row stride (144B)
#define PSS 72    // p row stride

__device__ __forceinline__ f32x4 mfma16(f16x8 a, f16x8 b, f32x4 c){
  return __builtin_amdgcn_mfma_f32_16x16x32_f16(a, b, c, 0, 0, 0);
}

// ---------------- kernel 0: weights fp32 -> fp16 ----------------
__global__ __launch_bounds__(256) void k_cvt(const float* __restrict__ wqkv,
                                             const float* __restrict__ wproj,
                                             f16* __restrict__ wqkv_h,
                                             f16* __restrict__ wproj_h){
  int i = blockIdx.x*256 + threadIdx.x;
  for (int idx = i; idx < 768*256; idx += gridDim.x*256) wqkv_h[idx] = (f16)wqkv[idx];
  for (int idx = i; idx < 256*256; idx += gridDim.x*256) wproj_h[idx] = (f16)wproj[idx];
}

// ---------------- fused: LN + QKV + attention + proj ----------------
// Round-4 skeleton (8 waves, wave h owns head h) + phase-level register prefetch of
// weight B-fragments + minimal barriers (6). 1 block/CU (157KB LDS) by design.
__global__ __launch_bounds__(512, 2) void k_fused(const float* __restrict__ x,
    const float* __restrict__ gamma, const float* __restrict__ beta,
    const f16* __restrict__ wqkv, const f16* __restrict__ wproj,
    const float* __restrict__ bproj, float* __restrict__ out)
{
  __shared__ __align__(16) f16 xn[64*XNS];      // 33792 B; overlaid by al after barrier 5
  __shared__ __align__(16) f16 perw[8][7424];   // per-wave qs/ks/vts (ps overlays qs+ks)
  __shared__ float red[2][8][64];
  __shared__ float mrs2[2][64];

  const int t = threadIdx.x;
  const int lane = t & 63;
  const int h = t >> 6;                 // wave id == head id
  const int l15 = lane & 15, l16 = lane >> 4;
  const int row = blockIdx.x;
  const int b = row >> 6, hh = row & 63;
  const float* xrow = x + (size_t)b*256*4096 + hh*64;

  // ---- prefetch Q-phase weights (issued first; in regs by end of LN) ----
  f16x8 bq[16];
  {
    const f16* wq = wqkv + (size_t)(h*32)*256;
    #pragma unroll
    for (int n = 0; n < 2; ++n)
      #pragma unroll
      for (int kk = 0; kk < 8; ++kk)
        bq[n*8+kk] = *(const f16x8*)&wq[(size_t)(n*16 + l15)*256 + kk*32 + l16*8];
  }

  // ---- x ingest: 16 lanes x float4 = 256B contiguous per (it,h,l16) row ----
  {
    float4 xv[8];
    #pragma unroll
    for (int it = 0; it < 8; ++it){
      int c = it*32 + h*4 + l16;
      xv[it] = *(const float4*)&xrow[(size_t)c*4096 + l15*4];
    }
    #pragma unroll
    for (int it = 0; it < 8; ++it){
      int c = it*32 + h*4 + l16;
      int w0 = l15*4;
      xn[(w0+0)*XNS + c] = (f16)xv[it].x;
      xn[(w0+1)*XNS + c] = (f16)xv[it].y;
      xn[(w0+2)*XNS + c] = (f16)xv[it].z;
      xn[(w0+3)*XNS + c] = (f16)xv[it].w;
    }
  }
  __syncthreads();   // (1) xn raw complete

  // ---- LN stats: wave h covers channels h*32..+31 at w=lane ----
  {
    float ssum = 0.f, s2 = 0.f;
    #pragma unroll
    for (int j8 = 0; j8 < 4; ++j8){
      f16x8 v = *(const f16x8*)&xn[lane*XNS + h*32 + j8*8];
      #pragma unroll
      for (int e = 0; e < 8; ++e){ float f = (float)v[e]; ssum += f; s2 += f*f; }
    }
    red[0][h][lane] = ssum; red[1][h][lane] = s2;
  }
  __syncthreads();   // (2)
  if (t < 64){
    float ss = 0.f, qq = 0.f;
    for (int j = 0; j < 8; ++j){ ss += red[0][j][t]; qq += red[1][j][t]; }
    float mu = ss*(1.f/256.f);
    float var = qq*(1.f/256.f) - mu*mu;
    mrs2[0][t] = mu; mrs2[1][t] = rsqrtf(var + 1e-5f);
  }
  __syncthreads();   // (3)
  {
    float mu = mrs2[0][lane], rs = mrs2[1][lane];
    #pragma unroll
    for (int j8 = 0; j8 < 4; ++j8){
      f16x8 v = *(const f16x8*)&xn[lane*XNS + h*32 + j8*8];
      f16x8 o;
      #pragma unroll
      for (int e = 0; e < 8; ++e){
        int c = h*32 + j8*8 + e;
        o[e] = (f16)(((float)v[e] - mu)*rs*gamma[c] + beta[c]);
      }
      *(f16x8*)&xn[lane*XNS + h*32 + j8*8] = o;
    }
  }
  __syncthreads();   // (4) xn normalized

  f16* qs  = &perw[h][0];
  f16* ks  = &perw[h][2560];
  f16* vts = &perw[h][5120];
  f16* ps  = &perw[h][0];      // overlays qs+ks (same-wave data only)

  // ---- Q phase: issue bk, compute with bq ----
  f16x8 bk[16];
  {
    const f16* wk = wqkv + (size_t)(256 + h*32)*256;
    #pragma unroll
    for (int n = 0; n < 2; ++n)
      #pragma unroll
      for (int kk = 0; kk < 8; ++kk)
        bk[n*8+kk] = *(const f16x8*)&wk[(size_t)(n*16 + l15)*256 + kk*32 + l16*8];
  }
  {
    f32x4 acc[4][2] = {};
    #pragma unroll
    for (int kk = 0; kk < 8; ++kk){
      int k0 = kk*32 + l16*8;
      f16x8 a[4];
      #pragma unroll
      for (int m = 0; m < 4; ++m) a[m] = *(const f16x8*)&xn[(m*16 + l15)*XNS + k0];
      #pragma unroll
      for (int m = 0; m < 4; ++m)
        #pragma unroll
        for (int n = 0; n < 2; ++n)
          acc[m][n] = mfma16(a[m], bq[n*8+kk], acc[m][n]);
    }
    #pragma unroll
    for (int m = 0; m < 4; ++m)
      for (int n = 0; n < 2; ++n)
        for (int r = 0; r < 4; ++r)
          qs[(m*16 + l16*4 + r)*QKS + n*16 + l15] = (f16)acc[m][n][r];
  }

  // ---- K phase: issue bv, compute with bk ----
  f16x8 bv[16];
  {
    const f16* wv = wqkv + (size_t)(512 + h*32)*256;
    #pragma unroll
    for (int n = 0; n < 2; ++n)
      #pragma unroll
      for (int kk = 0; kk < 8; ++kk)
        bv[n*8+kk] = *(const f16x8*)&wv[(size_t)(n*16 + l15)*256 + kk*32 + l16*8];
  }
  {
    f32x4 acc[4][2] = {};
    #pragma unroll
    for (int kk = 0; kk < 8; ++kk){
      int k0 = kk*32 + l16*8;
      f16x8 a[4];
      #pragma unroll
      for (int m = 0; m < 4; ++m) a[m] = *(const f16x8*)&xn[(m*16 + l15)*XNS + k0];
      #pragma unroll
      for (int m = 0; m < 4; ++m)
        #pragma unroll
        for (int n = 0; n < 2; ++n)
          acc[m][n] = mfma16(a[m], bk[n*8+kk], acc[m][n]);
    }
    #pragma unroll
    for (int m = 0; m < 4; ++m)
      for (int n = 0; n < 2; ++n)
        for (int r = 0; r < 4; ++r)
          ks[(m*16 + l16*4 + r)*QKS + n*16 + l15] = (f16)acc[m][n][r];
  }

  // ---- V phase (swapped: A = Wv fragments = bv, B = xn) -> vt[d][pos] ----
  {
    f32x4 acc[2][4] = {};
    #pragma unroll
    for (int kk = 0; kk < 8; ++kk){
      int k0 = kk*32 + l16*8;
      f16x8 bb[4];
      #pragma unroll
      for (int n = 0; n < 4; ++n) bb[n] = *(const f16x8*)&xn[(n*16 + l15)*XNS + k0];
      #pragma unroll
      for (int m = 0; m < 2; ++m)
        #pragma unroll
        for (int n = 0; n < 4; ++n)
          acc[m][n] = mfma16(bv[m*8+kk], bb[n], acc[m][n]);
    }
    #pragma unroll
    for (int m = 0; m < 2; ++m)
      for (int n = 0; n < 4; ++n)
        for (int r = 0; r < 4; ++r){
          int d   = m*16 + l16*4 + r;
          int pos = n*16 + l15;
          vts[d*VTS + pos] = (f16)acc[m][n][r];
        }
  }

  // ---- prefetch proj weights (in flight during attention) ----
  f16x8 bp[16];
  {
    const f16* wp = wproj + (size_t)(h*32)*256;
    #pragma unroll
    for (int n = 0; n < 2; ++n)
      #pragma unroll
      for (int kk = 0; kk < 8; ++kk)
        bp[n*8+kk] = *(const f16x8*)&wp[(size_t)(n*16 + l15)*256 + kk*32 + l16*8];
  }
  __syncthreads();   // (5) all xn reads done -> al overlay safe

  // ---- attention for head h (all same-wave; no barriers) ----
  f32x4 sa[4][4];
  {
    int k0 = l16*8;
    f16x8 a[4], bb[4];
    #pragma unroll
    for (int m = 0; m < 4; ++m) a[m]  = *(const f16x8*)&qs[(m*16 + l15)*QKS + k0];
    #pragma unroll
    for (int n = 0; n < 4; ++n) bb[n] = *(const f16x8*)&ks[(n*16 + l15)*QKS + k0];
    f32x4 z = {0.f,0.f,0.f,0.f};
    #pragma unroll
    for (int m = 0; m < 4; ++m)
      #pragma unroll
      for (int n = 0; n < 4; ++n)
        sa[m][n] = mfma16(a[m], bb[n], z);
  }
  {
    const float sc = 0.17677669529663687f;   // 32^-0.5
    #pragma unroll
    for (int m = 0; m < 4; ++m)
      #pragma unroll
      for (int r = 0; r < 4; ++r){
        float mx = fmaxf(fmaxf(sa[m][0][r], sa[m][1][r]), fmaxf(sa[m][2][r], sa[m][3][r]));
        mx = fmaxf(mx, __shfl_xor(mx, 1));
        mx = fmaxf(mx, __shfl_xor(mx, 2));
        mx = fmaxf(mx, __shfl_xor(mx, 4));
        mx = fmaxf(mx, __shfl_xor(mx, 8));
        float pv[4], sum = 0.f;
        #pragma unroll
        for (int n = 0; n < 4; ++n){ float p = __expf((sa[m][n][r] - mx)*sc); pv[n] = p; sum += p; }
        sum += __shfl_xor(sum, 1);
        sum += __shfl_xor(sum, 2);
        sum += __shfl_xor(sum, 4);
        sum += __shfl_xor(sum, 8);
        float inv = 1.f/sum;
        int q = m*16 + l16*4 + r;
        #pragma unroll
        for (int n = 0; n < 4; ++n) ps[q*PSS + n*16 + l15] = (f16)(pv[n]*inv);
      }
  }
  f16* al = xn;      // attn-out tile overlays xn
  {
    f32x4 oa[4][2] = {};
    #pragma unroll
    for (int kk = 0; kk < 2; ++kk){
      int k0 = kk*32 + l16*8;
      f16x8 a[4], bb[2];
      #pragma unroll
      for (int m = 0; m < 4; ++m) a[m]  = *(const f16x8*)&ps[(m*16 + l15)*PSS + k0];
      #pragma unroll
      for (int n = 0; n < 2; ++n) bb[n] = *(const f16x8*)&vts[(n*16 + l15)*VTS + k0];
      #pragma unroll
      for (int m = 0; m < 4; ++m)
        #pragma unroll
        for (int n = 0; n < 2; ++n)
          oa[m][n] = mfma16(a[m], bb[n], oa[m][n]);
    }
    #pragma unroll
    for (int m = 0; m < 4; ++m)
      for (int n = 0; n < 2; ++n)
        for (int r = 0; r < 4; ++r){
          int pos = m*16 + l16*4 + r;
          al[pos*XNS + h*32 + n*16 + l15] = (f16)oa[m][n][r];
        }
  }
  __syncthreads();   // (6) al complete from all waves

  // ---- out-proj with prefetched bp + direct f32x4 stores ----
  {
    f32x4 acc[4][2] = {};
    #pragma unroll
    for (int kk = 0; kk < 8; ++kk){
      int k0 = kk*32 + l16*8;
      f16x8 a[4];
      #pragma unroll
      for (int m = 0; m < 4; ++m) a[m] = *(const f16x8*)&al[(m*16 + l15)*XNS + k0];
      #pragma unroll
      for (int m = 0; m < 4; ++m)
        #pragma unroll
        for (int n = 0; n < 2; ++n)
          acc[m][n] = mfma16(a[m], bp[n*8+kk], acc[m][n]);
    }
    float bia[2];
    #pragma unroll
    for (int n = 0; n < 2; ++n) bia[n] = bproj[h*32 + n*16 + l15];
    float* obase = out + (size_t)b*256*4096 + hh*64;
    #pragma unroll
    for (int m = 0; m < 4; ++m)
      #pragma unroll
      for (int n = 0; n < 2; ++n){
        int dout = h*32 + n*16 + l15;
        f32x4 v;
        #pragma unroll
        for (int r = 0; r < 4; ++r) v[r] = acc[m][n][r] + bia[n];
        *(f32x4*)&obase[(size_t)dout*4096 + m*16 + l16*4] = v;
      }
  }
}

extern "C" void kernel_launch(void* const* d_in, const int* in_sizes, int n_in,
                              void* d_out, int out_size, void* d_ws, size_t ws_size,
                              hipStream_t stream)
{
  const float* x     = (const float*)d_in[0];
  const float* wqkv  = (const float*)d_in[1];
  const float* wproj = (const float*)d_in[2];
  const float* bproj = (const float*)d_in[3];
  const float* gamma = (const float*)d_in[4];
  const float* beta  = (const float*)d_in[5];
  float* out = (float*)d_out;

  f16* ws = (f16*)d_ws;
  f16* wqkv_h  = ws;            // 196608 f16
  f16* wproj_h = ws + 196608;   // 65536 f16

  k_cvt  <<<256, 256, 0, stream>>>(wqkv, wproj, wqkv_h, wproj_h);
  k_fused<<<1024, 512, 0, stream>>>(x, gamma, beta, wqkv_h, wproj_h, bproj, out);
}

// Round 10
// 201.664 us; speedup vs baseline: 1.4072x; 1.0485x over previous
//
#include <hip/hip_runtime.h>

typedef _Float16 f16;
typedef _Float16 f16x4 __attribute__((ext_vector_type(4)));
typedef _Float16 f16x8 __attribute__((ext_vector_type(8)));
typedef float f32x4 __attribute__((ext_vector_type(4)));

#define XNS 264   // xn row stride in f16 (528B = 33*16B)
#define QKS 40    // q/k row stride (80B) -- rows are 32 wide
#define VTS 72    // vt row stride (144B) -- rows are 64 wide
#define PSS 40    // p-HALF row stride (80B) -- rows are 32 wide (half of kpos)
#define SLOT 5120 // f16 per wave slot: qs[0:2560) ks[2560:5120); ps-half overlays qs, vt overlays ks

__device__ __forceinline__ f32x4 mfma16(f16x8 a, f16x8 b, f32x4 c){
  return __builtin_amdgcn_mfma_f32_16x16x32_f16(a, b, c, 0, 0, 0);
}

// ---------------- kernel 0: weights fp32 -> fp16 ----------------
__global__ __launch_bounds__(256) void k_cvt(const float* __restrict__ wqkv,
                                             const float* __restrict__ wproj,
                                             f16* __restrict__ wqkv_h,
                                             f16* __restrict__ wproj_h){
  int i = blockIdx.x*256 + threadIdx.x;
  for (int idx = i; idx < 768*256; idx += gridDim.x*256) wqkv_h[idx] = (f16)wqkv[idx];
  for (int idx = i; idx < 256*256; idx += gridDim.x*256) wproj_h[idx] = (f16)wproj[idx];
}

// ---------------- fused: LN + QKV + attention + proj ----------------
// 256 thr = 4 waves; wave w owns heads {w, w+4} sequentially. LDS 74752 B -> 2 blocks/CU
// (independent blocks cover each other's barrier drains). 5 barriers.
// P is processed in two 32-kpos halves so it fits the dead qs region at stride 40.
__global__ __launch_bounds__(256, 2) void k_fused(const float* __restrict__ x,
    const float* __restrict__ gamma, const float* __restrict__ beta,
    const f16* __restrict__ wqkv, const f16* __restrict__ wproj,
    const float* __restrict__ bproj, float* __restrict__ out)
{
  __shared__ __align__(16) f16 xn[64*XNS];      // 33792 B (stays intact throughout)
  __shared__ __align__(16) f16 perw[4][SLOT];   // 40960 B; red overlays start; al overlays all at end

  const int t = threadIdx.x;
  const int lane = t & 63;
  const int w = t >> 6;                 // wave id 0..3
  const int l15 = lane & 15, l16 = lane >> 4;
  const int row = blockIdx.x;
  const int b = row >> 6, hh = row & 63;
  const float* xrow = x + (size_t)b*256*4096 + hh*64;

  // ---- prefetch wq for head h0=w (in flight during ingest/LN) ----
  f16x8 bq[2][16];
  {
    const f16* wq = wqkv + (size_t)(w*32)*256;
    #pragma unroll
    for (int n = 0; n < 2; ++n)
      #pragma unroll
      for (int kk = 0; kk < 8; ++kk)
        bq[0][n*8+kk] = *(const f16x8*)&wq[(size_t)(n*16 + l15)*256 + kk*32 + l16*8];
  }

  // ---- ingest: c = t (64 lanes -> 64 consecutive 2B cols = conflict-free LDS writes) ----
  {
    const int c = t;
    #pragma unroll
    for (int j = 0; j < 16; ++j){
      float4 v = *(const float4*)&xrow[(size_t)c*4096 + j*4];
      xn[(j*4+0)*XNS + c] = (f16)v.x;
      xn[(j*4+1)*XNS + c] = (f16)v.y;
      xn[(j*4+2)*XNS + c] = (f16)v.z;
      xn[(j*4+3)*XNS + c] = (f16)v.w;
    }
  }
  __syncthreads();   // B1: xn raw complete

  // ---- LN stats: wave w covers channels w*64..+63 of row=lane ----
  float mu, rs;
  {
    float* red = (float*)&perw[0][0];   // [2][4][64] f32 overlay (dead before first GEMM)
    float s = 0.f, s2 = 0.f;
    #pragma unroll
    for (int j8 = 0; j8 < 8; ++j8){
      f16x8 v = *(const f16x8*)&xn[lane*XNS + w*64 + j8*8];
      #pragma unroll
      for (int e = 0; e < 8; ++e){ float f = (float)v[e]; s += f; s2 += f*f; }
    }
    red[w*64 + lane] = s;
    red[256 + w*64 + lane] = s2;
    __syncthreads();   // B2
    float ss = 0.f, qq = 0.f;
    #pragma unroll
    for (int j = 0; j < 4; ++j){ ss += red[j*64 + lane]; qq += red[256 + j*64 + lane]; }
    mu = ss*(1.f/256.f);
    rs = rsqrtf(qq*(1.f/256.f) - mu*mu + 1e-5f);
  }
  // ---- normalize in place (row=lane, cols w*64..+63) ----
  {
    #pragma unroll
    for (int j8 = 0; j8 < 8; ++j8){
      int c0 = w*64 + j8*8;
      f16x8 v = *(const f16x8*)&xn[lane*XNS + c0];
      f16x8 o;
      #pragma unroll
      for (int e = 0; e < 8; ++e)
        o[e] = (f16)(((float)v[e] - mu)*rs*gamma[c0+e] + beta[c0+e]);
      *(f16x8*)&xn[lane*XNS + c0] = o;
    }
  }
  __syncthreads();   // B3: xn normalized

  f16* qs  = &perw[w][0];
  f16* ks  = &perw[w][2560];
  f16* vts = &perw[w][2560];   // overlays ks (V computed after S)
  f16* ps  = &perw[w][0];      // 64x32 P-half, overlays qs (written after S reads)

  f16x4 oh[2][4][2];           // PV outputs for both heads, held in regs
  f16x8 bk[16], bv[16], bplo[16];

  #pragma unroll
  for (int hi = 0; hi < 2; ++hi){
    const int head = w + hi*4;

    // issue wk(head)
    {
      const f16* wk = wqkv + (size_t)(256 + head*32)*256;
      #pragma unroll
      for (int n = 0; n < 2; ++n)
        #pragma unroll
        for (int kk = 0; kk < 8; ++kk)
          bk[n*8+kk] = *(const f16x8*)&wk[(size_t)(n*16 + l15)*256 + kk*32 + l16*8];
    }
    // ---- Q GEMM (uses bq[hi]) ----
    {
      f32x4 acc[4][2] = {};
      #pragma unroll
      for (int kk = 0; kk < 8; ++kk){
        int k0 = kk*32 + l16*8;
        f16x8 a[4];
        #pragma unroll
        for (int m = 0; m < 4; ++m) a[m] = *(const f16x8*)&xn[(m*16 + l15)*XNS + k0];
        #pragma unroll
        for (int m = 0; m < 4; ++m)
          #pragma unroll
          for (int n = 0; n < 2; ++n)
            acc[m][n] = mfma16(a[m], bq[hi][n*8+kk], acc[m][n]);
      }
      #pragma unroll
      for (int m = 0; m < 4; ++m)
        for (int n = 0; n < 2; ++n)
          for (int r = 0; r < 4; ++r)
            qs[(m*16 + l16*4 + r)*QKS + n*16 + l15] = (f16)acc[m][n][r];
    }
    // issue wv(head)
    {
      const f16* wv = wqkv + (size_t)(512 + head*32)*256;
      #pragma unroll
      for (int n = 0; n < 2; ++n)
        #pragma unroll
        for (int kk = 0; kk < 8; ++kk)
          bv[n*8+kk] = *(const f16x8*)&wv[(size_t)(n*16 + l15)*256 + kk*32 + l16*8];
    }
    // ---- K GEMM (uses bk) ----
    {
      f32x4 acc[4][2] = {};
      #pragma unroll
      for (int kk = 0; kk < 8; ++kk){
        int k0 = kk*32 + l16*8;
        f16x8 a[4];
        #pragma unroll
        for (int m = 0; m < 4; ++m) a[m] = *(const f16x8*)&xn[(m*16 + l15)*XNS + k0];
        #pragma unroll
        for (int m = 0; m < 4; ++m)
          #pragma unroll
          for (int n = 0; n < 2; ++n)
            acc[m][n] = mfma16(a[m], bk[n*8+kk], acc[m][n]);
      }
      #pragma unroll
      for (int m = 0; m < 4; ++m)
        for (int n = 0; n < 2; ++n)
          for (int r = 0; r < 4; ++r)
            ks[(m*16 + l16*4 + r)*QKS + n*16 + l15] = (f16)acc[m][n][r];
    }
    // ---- S = Q K^T (wave-local) ----
    f32x4 sa[4][4];
    {
      int k0 = l16*8;
      f16x8 a[4], bb[4];
      #pragma unroll
      for (int m = 0; m < 4; ++m) a[m]  = *(const f16x8*)&qs[(m*16 + l15)*QKS + k0];
      #pragma unroll
      for (int n = 0; n < 4; ++n) bb[n] = *(const f16x8*)&ks[(n*16 + l15)*QKS + k0];
      f32x4 z = {0.f,0.f,0.f,0.f};
      #pragma unroll
      for (int m = 0; m < 4; ++m)
        #pragma unroll
        for (int n = 0; n < 4; ++n)
          sa[m][n] = mfma16(a[m], bb[n], z);
    }
    // ---- softmax fully in registers (sa becomes normalized P) ----
    {
      const float sc = 0.17677669529663687f;   // 32^-0.5
      #pragma unroll
      for (int m = 0; m < 4; ++m)
        #pragma unroll
        for (int r = 0; r < 4; ++r){
          float mx = fmaxf(fmaxf(sa[m][0][r], sa[m][1][r]), fmaxf(sa[m][2][r], sa[m][3][r]));
          mx = fmaxf(mx, __shfl_xor(mx, 1));
          mx = fmaxf(mx, __shfl_xor(mx, 2));
          mx = fmaxf(mx, __shfl_xor(mx, 4));
          mx = fmaxf(mx, __shfl_xor(mx, 8));
          float pv[4], sum = 0.f;
          #pragma unroll
          for (int n = 0; n < 4; ++n){ float p = __expf((sa[m][n][r] - mx)*sc); pv[n] = p; sum += p; }
          sum += __shfl_xor(sum, 1);
          sum += __shfl_xor(sum, 2);
          sum += __shfl_xor(sum, 4);
          sum += __shfl_xor(sum, 8);
          float inv = 1.f/sum;
          #pragma unroll
          for (int n = 0; n < 4; ++n) sa[m][n][r] = pv[n]*inv;
        }
    }
    // issue next phase's weights: hi==0 -> wq(head+4); hi==1 -> proj lo-half
    if (hi == 0){
      const f16* wq = wqkv + (size_t)((w+4)*32)*256;
      #pragma unroll
      for (int n = 0; n < 2; ++n)
        #pragma unroll
        for (int kk = 0; kk < 8; ++kk)
          bq[1][n*8+kk] = *(const f16x8*)&wq[(size_t)(n*16 + l15)*256 + kk*32 + l16*8];
    } else {
      const f16* wp = wproj + (size_t)(w*64)*256;
      #pragma unroll
      for (int n = 0; n < 2; ++n)
        #pragma unroll
        for (int kk = 0; kk < 8; ++kk)
          bplo[n*8+kk] = *(const f16x8*)&wp[(size_t)(n*16 + l15)*256 + kk*32 + l16*8];
    }
    // ---- V GEMM swapped (A = bv -> d rows, B = xn -> pos); vt overlays ks (dead) ----
    {
      f32x4 acc[2][4] = {};
      #pragma unroll
      for (int kk = 0; kk < 8; ++kk){
        int k0 = kk*32 + l16*8;
        f16x8 bb[4];
        #pragma unroll
        for (int n = 0; n < 4; ++n) bb[n] = *(const f16x8*)&xn[(n*16 + l15)*XNS + k0];
        #pragma unroll
        for (int m = 0; m < 2; ++m)
          #pragma unroll
          for (int n = 0; n < 4; ++n)
            acc[m][n] = mfma16(bv[m*8+kk], bb[n], acc[m][n]);
      }
      #pragma unroll
      for (int m = 0; m < 2; ++m)
        for (int n = 0; n < 4; ++n)
          for (int r = 0; r < 4; ++r){
            int d   = m*16 + l16*4 + r;
            int pos = n*16 + l15;
            vts[d*VTS + pos] = (f16)acc[m][n][r];
          }
    }
    // ---- PV in two kpos-halves: 64x32 P-half at stride 40 fits dead qs region ----
    {
      f32x4 oa[4][2] = {};
      #pragma unroll
      for (int half = 0; half < 2; ++half){
        // write P-half (cols half*32..+31 of P) from registers
        #pragma unroll
        for (int m = 0; m < 4; ++m)
          #pragma unroll
          for (int n2 = 0; n2 < 2; ++n2)
            #pragma unroll
            for (int r = 0; r < 4; ++r)
              ps[(m*16 + l16*4 + r)*PSS + n2*16 + l15] = (f16)sa[m][half*2+n2][r];
        // PV partial: global kpos = half*32 + local k
        int k0 = half*32 + l16*8;
        f16x8 a[4], bb[2];
        #pragma unroll
        for (int m = 0; m < 4; ++m) a[m]  = *(const f16x8*)&ps[(m*16 + l15)*PSS + l16*8];
        #pragma unroll
        for (int n = 0; n < 2; ++n) bb[n] = *(const f16x8*)&vts[(n*16 + l15)*VTS + k0];
        #pragma unroll
        for (int m = 0; m < 4; ++m)
          #pragma unroll
          for (int n = 0; n < 2; ++n)
            oa[m][n] = mfma16(a[m], bb[n], oa[m][n]);
      }
      #pragma unroll
      for (int m = 0; m < 4; ++m)
        #pragma unroll
        for (int n = 0; n < 2; ++n)
          #pragma unroll
          for (int r = 0; r < 4; ++r)
            oh[hi][m][n][r] = (f16)oa[m][n][r];
    }
  }
  __syncthreads();   // B4: all slot reads done -> al may overlay perw

  // ---- al (64 pos x 256 ch, stride XNS) overlays perw region (33792B <= 40960B) ----
  f16* al = &perw[0][0];
  #pragma unroll
  for (int hi = 0; hi < 2; ++hi){
    int hc = (w + hi*4)*32;
    #pragma unroll
    for (int m = 0; m < 4; ++m)
      for (int n = 0; n < 2; ++n)
        for (int r = 0; r < 4; ++r)
          al[(m*16 + l16*4 + r)*XNS + hc + n*16 + l15] = oh[hi][m][n][r];
  }
  __syncthreads();   // B5: al complete

  // ---- out-proj: wave w -> channels w*64..+63; single K-loop, both halves ----
  f16x8 bphi[16];
  {
    const f16* wp = wproj + (size_t)(w*64)*256;
    #pragma unroll
    for (int n = 0; n < 2; ++n)
      #pragma unroll
      for (int kk = 0; kk < 8; ++kk)
        bphi[n*8+kk] = *(const f16x8*)&wp[(size_t)((n+2)*16 + l15)*256 + kk*32 + l16*8];
  }
  {
    f32x4 acc[4][4] = {};
    #pragma unroll
    for (int kk = 0; kk < 8; ++kk){
      int k0 = kk*32 + l16*8;
      f16x8 a[4];
      #pragma unroll
      for (int m = 0; m < 4; ++m) a[m] = *(const f16x8*)&al[(m*16 + l15)*XNS + k0];
      #pragma unroll
      for (int m = 0; m < 4; ++m){
        #pragma unroll
        for (int n = 0; n < 2; ++n){
          acc[m][n]   = mfma16(a[m], bplo[n*8+kk], acc[m][n]);
          acc[m][2+n] = mfma16(a[m], bphi[n*8+kk], acc[m][2+n]);
        }
      }
    }
    float bia[4];
    #pragma unroll
    for (int n = 0; n < 4; ++n) bia[n] = bproj[w*64 + n*16 + l15];
    float* obase = out + (size_t)b*256*4096 + hh*64;
    #pragma unroll
    for (int m = 0; m < 4; ++m)
      #pragma unroll
      for (int n = 0; n < 4; ++n){
        int dout = w*64 + n*16 + l15;
        f32x4 v;
        #pragma unroll
        for (int r = 0; r < 4; ++r) v[r] = acc[m][n][r] + bia[n];
        *(f32x4*)&obase[(size_t)dout*4096 + m*16 + l16*4] = v;
      }
  }
}

extern "C" void kernel_launch(void* const* d_in, const int* in_sizes, int n_in,
                              void* d_out, int out_size, void* d_ws, size_t ws_size,
                              hipStream_t stream)
{
  const float* x     = (const float*)d_in[0];
  const float* wqkv  = (const float*)d_in[1];
  const float* wproj = (const float*)d_in[2];
  const float* bproj = (const float*)d_in[3];
  const float* gamma = (const float*)d_in[4];
  const float* beta  = (const float*)d_in[5];
  float* out = (float*)d_out;

  f16* ws = (f16*)d_ws;
  f16* wqkv_h  = ws;            // 196608 f16
  f16* wproj_h = ws + 196608;   // 65536 f16

  k_cvt  <<<256, 256, 0, stream>>>(wqkv, wproj, wqkv_h, wproj_h);
  k_fused<<<1024, 256, 0, stream>>>(x, gamma, beta, wqkv_h, wproj_h, bproj, out);
}

// Round 11
// 200.462 us; speedup vs baseline: 1.4157x; 1.0060x over previous
//
#include <hip/hip_runtime.h>

typedef _Float16 f16;
typedef _Float16 f16x4 __attribute__((ext_vector_type(4)));
typedef _Float16 f16x8 __attribute__((ext_vector_type(8)));
typedef float f32x4 __attribute__((ext_vector_type(4)));

#define XNS 264   // xn row stride in f16 (528B = 33*16B)
#define QKS 40    // q/k row stride (80B) -- rows are 32 wide
#define VTS 72    // vt row stride (144B) -- rows are 64 wide
#define PSS 40    // p-HALF row stride (80B) -- rows are 32 wide (half of kpos)
#define SLOT 5120 // f16 per wave slot: qs[0:2560) ks[2560:5120); ps-half overlays qs, vt overlays ks

__device__ __forceinline__ f32x4 mfma16(f16x8 a, f16x8 b, f32x4 c){
  return __builtin_amdgcn_mfma_f32_16x16x32_f16(a, b, c, 0, 0, 0);
}

// ---------------- kernel 0: weights fp32 -> fp16 ----------------
__global__ __launch_bounds__(256) void k_cvt(const float* __restrict__ wqkv,
                                             const float* __restrict__ wproj,
                                             f16* __restrict__ wqkv_h,
                                             f16* __restrict__ wproj_h){
  int i = blockIdx.x*256 + threadIdx.x;
  for (int idx = i; idx < 768*256; idx += gridDim.x*256) wqkv_h[idx] = (f16)wqkv[idx];
  for (int idx = i; idx < 256*256; idx += gridDim.x*256) wproj_h[idx] = (f16)wproj[idx];
}

// ---------------- fused: LN + QKV + attention + proj ----------------
// 256 thr = 4 waves; wave w owns heads {w, w+4}. LDS 74752 B -> 2 blocks/CU.
// amdgpu_waves_per_eu(2,2): LDS already caps at 2 waves/EU, so pin the register
// allocator to the full 256-VGPR budget (round 10: allocator chose 128 -> spills,
// +12MB scratch traffic in WRITE_SIZE).
__global__ __launch_bounds__(256)
__attribute__((amdgpu_waves_per_eu(2, 2)))
void k_fused(const float* __restrict__ x,
    const float* __restrict__ gamma, const float* __restrict__ beta,
    const f16* __restrict__ wqkv, const f16* __restrict__ wproj,
    const float* __restrict__ bproj, float* __restrict__ out)
{
  __shared__ __align__(16) f16 xn[64*XNS];      // 33792 B (stays intact throughout)
  __shared__ __align__(16) f16 perw[4][SLOT];   // 40960 B; red overlays start; al overlays all at end

  const int t = threadIdx.x;
  const int lane = t & 63;
  const int w = t >> 6;                 // wave id 0..3
  const int l15 = lane & 15, l16 = lane >> 4;
  const int row = blockIdx.x;
  const int b = row >> 6, hh = row & 63;
  const float* xrow = x + (size_t)b*256*4096 + hh*64;

  // ---- prefetch wq for head h0=w (in flight during ingest/LN) ----
  f16x8 bq[2][16];
  {
    const f16* wq = wqkv + (size_t)(w*32)*256;
    #pragma unroll
    for (int n = 0; n < 2; ++n)
      #pragma unroll
      for (int kk = 0; kk < 8; ++kk)
        bq[0][n*8+kk] = *(const f16x8*)&wq[(size_t)(n*16 + l15)*256 + kk*32 + l16*8];
  }

  // ---- ingest: c = t (64 lanes -> 64 consecutive 2B cols = conflict-free LDS writes) ----
  {
    const int c = t;
    #pragma unroll
    for (int j = 0; j < 16; ++j){
      float4 v = *(const float4*)&xrow[(size_t)c*4096 + j*4];
      xn[(j*4+0)*XNS + c] = (f16)v.x;
      xn[(j*4+1)*XNS + c] = (f16)v.y;
      xn[(j*4+2)*XNS + c] = (f16)v.z;
      xn[(j*4+3)*XNS + c] = (f16)v.w;
    }
  }
  __syncthreads();   // B1: xn raw complete

  // ---- LN stats: wave w covers channels w*64..+63 of row=lane ----
  float mu, rs;
  {
    float* red = (float*)&perw[0][0];   // [2][4][64] f32 overlay (dead before first GEMM)
    float s = 0.f, s2 = 0.f;
    #pragma unroll
    for (int j8 = 0; j8 < 8; ++j8){
      f16x8 v = *(const f16x8*)&xn[lane*XNS + w*64 + j8*8];
      #pragma unroll
      for (int e = 0; e < 8; ++e){ float f = (float)v[e]; s += f; s2 += f*f; }
    }
    red[w*64 + lane] = s;
    red[256 + w*64 + lane] = s2;
    __syncthreads();   // B2
    float ss = 0.f, qq = 0.f;
    #pragma unroll
    for (int j = 0; j < 4; ++j){ ss += red[j*64 + lane]; qq += red[256 + j*64 + lane]; }
    mu = ss*(1.f/256.f);
    rs = rsqrtf(qq*(1.f/256.f) - mu*mu + 1e-5f);
  }
  // ---- normalize in place (row=lane, cols w*64..+63) ----
  {
    #pragma unroll
    for (int j8 = 0; j8 < 8; ++j8){
      int c0 = w*64 + j8*8;
      f16x8 v = *(const f16x8*)&xn[lane*XNS + c0];
      f16x8 o;
      #pragma unroll
      for (int e = 0; e < 8; ++e)
        o[e] = (f16)(((float)v[e] - mu)*rs*gamma[c0+e] + beta[c0+e]);
      *(f16x8*)&xn[lane*XNS + c0] = o;
    }
  }
  __syncthreads();   // B3: xn normalized

  f16* qs  = &perw[w][0];
  f16* ks  = &perw[w][2560];
  f16* vts = &perw[w][2560];   // overlays ks (V computed after S)
  f16* ps  = &perw[w][0];      // 64x32 P-half, overlays qs (written after S reads)

  f16x4 oh[2][4][2];           // PV outputs for both heads, held in regs
  f16x8 bk[16], bv[16], bplo[16];

  #pragma unroll
  for (int hi = 0; hi < 2; ++hi){
    const int head = w + hi*4;

    // issue wk(head)
    {
      const f16* wk = wqkv + (size_t)(256 + head*32)*256;
      #pragma unroll
      for (int n = 0; n < 2; ++n)
        #pragma unroll
        for (int kk = 0; kk < 8; ++kk)
          bk[n*8+kk] = *(const f16x8*)&wk[(size_t)(n*16 + l15)*256 + kk*32 + l16*8];
    }
    // ---- Q GEMM (uses bq[hi]) ----
    {
      f32x4 acc[4][2] = {};
      #pragma unroll
      for (int kk = 0; kk < 8; ++kk){
        int k0 = kk*32 + l16*8;
        f16x8 a[4];
        #pragma unroll
        for (int m = 0; m < 4; ++m) a[m] = *(const f16x8*)&xn[(m*16 + l15)*XNS + k0];
        #pragma unroll
        for (int m = 0; m < 4; ++m)
          #pragma unroll
          for (int n = 0; n < 2; ++n)
            acc[m][n] = mfma16(a[m], bq[hi][n*8+kk], acc[m][n]);
      }
      #pragma unroll
      for (int m = 0; m < 4; ++m)
        for (int n = 0; n < 2; ++n)
          for (int r = 0; r < 4; ++r)
            qs[(m*16 + l16*4 + r)*QKS + n*16 + l15] = (f16)acc[m][n][r];
    }
    // issue wv(head)
    {
      const f16* wv = wqkv + (size_t)(512 + head*32)*256;
      #pragma unroll
      for (int n = 0; n < 2; ++n)
        #pragma unroll
        for (int kk = 0; kk < 8; ++kk)
          bv[n*8+kk] = *(const f16x8*)&wv[(size_t)(n*16 + l15)*256 + kk*32 + l16*8];
    }
    // ---- K GEMM (uses bk) ----
    {
      f32x4 acc[4][2] = {};
      #pragma unroll
      for (int kk = 0; kk < 8; ++kk){
        int k0 = kk*32 + l16*8;
        f16x8 a[4];
        #pragma unroll
        for (int m = 0; m < 4; ++m) a[m] = *(const f16x8*)&xn[(m*16 + l15)*XNS + k0];
        #pragma unroll
        for (int m = 0; m < 4; ++m)
          #pragma unroll
          for (int n = 0; n < 2; ++n)
            acc[m][n] = mfma16(a[m], bk[n*8+kk], acc[m][n]);
      }
      #pragma unroll
      for (int m = 0; m < 4; ++m)
        for (int n = 0; n < 2; ++n)
          for (int r = 0; r < 4; ++r)
            ks[(m*16 + l16*4 + r)*QKS + n*16 + l15] = (f16)acc[m][n][r];
    }
    // ---- S = Q K^T (wave-local) ----
    f32x4 sa[4][4];
    {
      int k0 = l16*8;
      f16x8 a[4], bb[4];
      #pragma unroll
      for (int m = 0; m < 4; ++m) a[m]  = *(const f16x8*)&qs[(m*16 + l15)*QKS + k0];
      #pragma unroll
      for (int n = 0; n < 4; ++n) bb[n] = *(const f16x8*)&ks[(n*16 + l15)*QKS + k0];
      f32x4 z = {0.f,0.f,0.f,0.f};
      #pragma unroll
      for (int m = 0; m < 4; ++m)
        #pragma unroll
        for (int n = 0; n < 4; ++n)
          sa[m][n] = mfma16(a[m], bb[n], z);
    }
    // ---- softmax fully in registers (sa becomes normalized P) ----
    {
      const float sc = 0.17677669529663687f;   // 32^-0.5
      #pragma unroll
      for (int m = 0; m < 4; ++m)
        #pragma unroll
        for (int r = 0; r < 4; ++r){
          float mx = fmaxf(fmaxf(sa[m][0][r], sa[m][1][r]), fmaxf(sa[m][2][r], sa[m][3][r]));
          mx = fmaxf(mx, __shfl_xor(mx, 1));
          mx = fmaxf(mx, __shfl_xor(mx, 2));
          mx = fmaxf(mx, __shfl_xor(mx, 4));
          mx = fmaxf(mx, __shfl_xor(mx, 8));
          float pv[4], sum = 0.f;
          #pragma unroll
          for (int n = 0; n < 4; ++n){ float p = __expf((sa[m][n][r] - mx)*sc); pv[n] = p; sum += p; }
          sum += __shfl_xor(sum, 1);
          sum += __shfl_xor(sum, 2);
          sum += __shfl_xor(sum, 4);
          sum += __shfl_xor(sum, 8);
          float inv = 1.f/sum;
          #pragma unroll
          for (int n = 0; n < 4; ++n) sa[m][n][r] = pv[n]*inv;
        }
    }
    // issue next phase's weights: hi==0 -> wq(head+4); hi==1 -> proj lo-half
    if (hi == 0){
      const f16* wq = wqkv + (size_t)((w+4)*32)*256;
      #pragma unroll
      for (int n = 0; n < 2; ++n)
        #pragma unroll
        for (int kk = 0; kk < 8; ++kk)
          bq[1][n*8+kk] = *(const f16x8*)&wq[(size_t)(n*16 + l15)*256 + kk*32 + l16*8];
    } else {
      const f16* wp = wproj + (size_t)(w*64)*256;
      #pragma unroll
      for (int n = 0; n < 2; ++n)
        #pragma unroll
        for (int kk = 0; kk < 8; ++kk)
          bplo[n*8+kk] = *(const f16x8*)&wp[(size_t)(n*16 + l15)*256 + kk*32 + l16*8];
    }
    // ---- V GEMM swapped (A = bv -> d rows, B = xn -> pos); vt overlays ks (dead) ----
    {
      f32x4 acc[2][4] = {};
      #pragma unroll
      for (int kk = 0; kk < 8; ++kk){
        int k0 = kk*32 + l16*8;
        f16x8 bb[4];
        #pragma unroll
        for (int n = 0; n < 4; ++n) bb[n] = *(const f16x8*)&xn[(n*16 + l15)*XNS + k0];
        #pragma unroll
        for (int m = 0; m < 2; ++m)
          #pragma unroll
          for (int n = 0; n < 4; ++n)
            acc[m][n] = mfma16(bv[m*8+kk], bb[n], acc[m][n]);
      }
      #pragma unroll
      for (int m = 0; m < 2; ++m)
        for (int n = 0; n < 4; ++n)
          for (int r = 0; r < 4; ++r){
            int d   = m*16 + l16*4 + r;
            int pos = n*16 + l15;
            vts[d*VTS + pos] = (f16)acc[m][n][r];
          }
    }
    // ---- PV in two kpos-halves: 64x32 P-half at stride 40 fits dead qs region ----
    {
      f32x4 oa[4][2] = {};
      #pragma unroll
      for (int half = 0; half < 2; ++half){
        // write P-half (cols half*32..+31 of P) from registers
        #pragma unroll
        for (int m = 0; m < 4; ++m)
          #pragma unroll
          for (int n2 = 0; n2 < 2; ++n2)
            #pragma unroll
            for (int r = 0; r < 4; ++r)
              ps[(m*16 + l16*4 + r)*PSS + n2*16 + l15] = (f16)sa[m][half*2+n2][r];
        // PV partial: global kpos = half*32 + local k
        int k0 = half*32 + l16*8;
        f16x8 a[4], bb[2];
        #pragma unroll
        for (int m = 0; m < 4; ++m) a[m]  = *(const f16x8*)&ps[(m*16 + l15)*PSS + l16*8];
        #pragma unroll
        for (int n = 0; n < 2; ++n) bb[n] = *(const f16x8*)&vts[(n*16 + l15)*VTS + k0];
        #pragma unroll
        for (int m = 0; m < 4; ++m)
          #pragma unroll
          for (int n = 0; n < 2; ++n)
            oa[m][n] = mfma16(a[m], bb[n], oa[m][n]);
      }
      #pragma unroll
      for (int m = 0; m < 4; ++m)
        #pragma unroll
        for (int n = 0; n < 2; ++n)
          #pragma unroll
          for (int r = 0; r < 4; ++r)
            oh[hi][m][n][r] = (f16)oa[m][n][r];
    }
  }
  __syncthreads();   // B4: all slot reads done -> al may overlay perw

  // ---- al (64 pos x 256 ch, stride XNS) overlays perw region (33792B <= 40960B) ----
  f16* al = &perw[0][0];
  #pragma unroll
  for (int hi = 0; hi < 2; ++hi){
    int hc = (w + hi*4)*32;
    #pragma unroll
    for (int m = 0; m < 4; ++m)
      for (int n = 0; n < 2; ++n)
        for (int r = 0; r < 4; ++r)
          al[(m*16 + l16*4 + r)*XNS + hc + n*16 + l15] = oh[hi][m][n][r];
  }
  __syncthreads();   // B5: al complete

  // ---- out-proj: wave w -> channels w*64..+63; single K-loop, both halves ----
  f16x8 bphi[16];
  {
    const f16* wp = wproj + (size_t)(w*64)*256;
    #pragma unroll
    for (int n = 0; n < 2; ++n)
      #pragma unroll
      for (int kk = 0; kk < 8; ++kk)
        bphi[n*8+kk] = *(const f16x8*)&wp[(size_t)((n+2)*16 + l15)*256 + kk*32 + l16*8];
  }
  {
    f32x4 acc[4][4] = {};
    #pragma unroll
    for (int kk = 0; kk < 8; ++kk){
      int k0 = kk*32 + l16*8;
      f16x8 a[4];
      #pragma unroll
      for (int m = 0; m < 4; ++m) a[m] = *(const f16x8*)&al[(m*16 + l15)*XNS + k0];
      #pragma unroll
      for (int m = 0; m < 4; ++m){
        #pragma unroll
        for (int n = 0; n < 2; ++n){
          acc[m][n]   = mfma16(a[m], bplo[n*8+kk], acc[m][n]);
          acc[m][2+n] = mfma16(a[m], bphi[n*8+kk], acc[m][2+n]);
        }
      }
    }
    float bia[4];
    #pragma unroll
    for (int n = 0; n < 4; ++n) bia[n] = bproj[w*64 + n*16 + l15];
    float* obase = out + (size_t)b*256*4096 + hh*64;
    #pragma unroll
    for (int m = 0; m < 4; ++m)
      #pragma unroll
      for (int n = 0; n < 4; ++n){
        int dout = w*64 + n*16 + l15;
        f32x4 v;
        #pragma unroll
        for (int r = 0; r < 4; ++r) v[r] = acc[m][n][r] + bia[n];
        *(f32x4*)&obase[(size_t)dout*4096 + m*16 + l16*4] = v;
      }
  }
}

extern "C" void kernel_launch(void* const* d_in, const int* in_sizes, int n_in,
                              void* d_out, int out_size, void* d_ws, size_t ws_size,
                              hipStream_t stream)
{
  const float* x     = (const float*)d_in[0];
  const float* wqkv  = (const float*)d_in[1];
  const float* wproj = (const float*)d_in[2];
  const float* bproj = (const float*)d_in[3];
  const float* gamma = (const float*)d_in[4];
  const float* beta  = (const float*)d_in[5];
  float* out = (float*)d_out;

  f16* ws = (f16*)d_ws;
  f16* wqkv_h  = ws;            // 196608 f16
  f16* wproj_h = ws + 196608;   // 65536 f16

  k_cvt  <<<256, 256, 0, stream>>>(wqkv, wproj, wqkv_h, wproj_h);
  k_fused<<<1024, 256, 0, stream>>>(x, gamma, beta, wqkv_h, wproj_h, bproj, out);
}